// Round 5
// baseline (511.275 us; speedup 1.0000x reference)
//
#include <hip/hip_runtime.h>

// ASG loss, B=128 T=4000 N=64 L=101.
// R5: identical math to R4 (passed, absmax 0.0), repacked for occupancy.
//   R4 launched 4352 single-wave workgroups -> only ~4 waves/CU resident
//   (13% occupancy), leaving the 550-cyc/step latency chain unhidden.
//   R5 packs 8 independent waves per 512-thread workgroup (no barriers;
//   per-wave LDS slices): 544 blocks -> ~17 waves/CU resident.
//   Denominator: overlap-and-discard segmented scan (NSEG=32, WARM=40),
//   linear-space fdot2 matvec with per-step rescale.
//   Numerator: R2-verified fwd/bwd log2-domain chains (blocks 0..31).

#define TT 4000
#define NN 64
#define LL 101
#define NSEG 32
#define SEGN 125          // steps per segment (last segment: 124)
#define WARM 40
#define NUMW 256          // numerator waves (= 32 blocks of 8)

static constexpr float L2E  = 1.44269504088896340736f;   // log2(e)
static constexpr float LN2F = 0.69314718055994530942f;
static constexpr float NEG2 = -1.0e30f;

// ws layout (floats) - total ~132 KB
#define WS_X    0                      // [128][NSEG] per-segment log2 ratios
#define WS_NF   4096                   // [128][112] fwd numer (log2) at t=1999
#define WS_HB   18432                  // [128][112] bwd numer (log2) at t=2000
#define WS_LOSS 32768                  // [128] per-batch loss

#if defined(__has_builtin)
#if __has_builtin(__builtin_amdgcn_fdot2)
#define USE_FDOT2 1
#endif
#endif
#ifndef USE_FDOT2
#define USE_FDOT2 0
#endif

typedef _Float16 h2 __attribute__((ext_vector_type(2)));

__device__ __forceinline__ float wsum64(float v) {
  v += __shfl_xor(v, 1);  v += __shfl_xor(v, 2);  v += __shfl_xor(v, 4);
  v += __shfl_xor(v, 8);  v += __shfl_xor(v, 16); v += __shfl_xor(v, 32);
  return v;
}

__global__ __launch_bounds__(512) void asg_main(
    const float* __restrict__ E, const float* __restrict__ TR,
    const int* __restrict__ Y, float* __restrict__ ws)
{
  const int w    = threadIdx.x >> 6;           // wave in block (0..7)
  const int lane = threadIdx.x & 63;
  const int gw   = blockIdx.x * 8 + w;         // global wave id

#if USE_FDOT2
  __shared__ _Float16 PS[8][2][64];            // per-wave slices
#else
  __shared__ float PS[8][2][64];
#endif

  if (gw >= NUMW) {
    // ================= denominator segment (1 wave) =================
    const int dw = gw - NUMW;
    const int b  = dw >> 5;            // NSEG = 32
    const int s  = dw & 31;
    const float* em = E + (size_t)b * TT * NN;
    const int i = lane;
#if USE_FDOT2
    _Float16 (*psw)[64] = PS[w];
#else
    float (*psw)[64] = PS[w];
#endif

#if USE_FDOT2
    h2 W2[32];
#pragma unroll
    for (int k = 0; k < 32; ++k) {
      const float w0 = TR[(i + 1) * NN + 2 * k];
      const float w1 = TR[(i + 1) * NN + 2 * k + 1];
      h2 t; t.x = (_Float16)exp2f(w0 * L2E); t.y = (_Float16)exp2f(w1 * L2E);
      W2[k] = t;
    }
#else
    const int h0 = (i >> 5) << 5;      // pair-split: states {i, i^32}
    const int ip = i ^ 32;
    float WA[32], WB[32];
#pragma unroll
    for (int k = 0; k < 32; ++k) {
      const int j = h0 + k;
      WA[k] = exp2f(TR[(i + 1) * NN + j] * L2E);
      WB[k] = exp2f(TR[(ip + 1) * NN + j] * L2E);
    }
#endif

    const int t0    = 1 + SEGN * s;
    const int nmain = (s == NSEG - 1) ? (TT - t0) : SEGN;
    float Pl, Csum;
    if (s == 0) {
      const float a0  = (em[i] + TR[i]) * L2E;
      const float a00 = __shfl(a0, 0);
      Csum = a00;
      Pl   = exp2f(a0 - a00);
    } else {
      Csum = 0.f;
      Pl   = 1.0f;
    }
#if USE_FDOT2
    psw[0][i] = (_Float16)Pl;
#else
    psw[0][i] = Pl;
#endif
    asm volatile("" ::: "memory");
    int buf = 0;

#define EML(t) em[(size_t)((t) < (TT - 1) ? (t) : (TT - 1)) * NN + i]

#if USE_FDOT2
#define BCH2(x) __builtin_bit_cast(h2, (x))
#define D4(u, k)                                                               \
    c0 = __builtin_amdgcn_fdot2(BCH2(u.x), W2[k], c0, false);                  \
    c1 = __builtin_amdgcn_fdot2(BCH2(u.y), W2[k + 1], c1, false);              \
    c2 = __builtin_amdgcn_fdot2(BCH2(u.z), W2[k + 2], c2, false);              \
    c3 = __builtin_amdgcn_fdot2(BCH2(u.w), W2[k + 3], c3, false);

#define DSTEP(EC)                                                              \
    {                                                                          \
      const uint4* pv = (const uint4*)&psw[buf][0];                            \
      const uint4 u0 = pv[0], u1 = pv[1], u2 = pv[2], u3 = pv[3];              \
      const uint4 u4 = pv[4], u5 = pv[5], u6 = pv[6], u7 = pv[7];              \
      float c0 = 0.f, c1 = 0.f, c2 = 0.f, c3 = 0.f;                            \
      D4(u0, 0)  D4(u1, 4)  D4(u2, 8)  D4(u3, 12)                              \
      D4(u4, 16) D4(u5, 20) D4(u6, 24) D4(u7, 28)                              \
      const float P0 = (float)BCH2(u0.x).x;                                    \
      const float S = (c0 + c1) + (c2 + c3);                                   \
      Pl = S * __builtin_amdgcn_rcpf(P0) * exp2f(fmaf((EC), L2E, -6.f));       \
      Csum += log2f(P0) + 6.f;                                                 \
      psw[buf ^ 1][i] = (_Float16)fminf(Pl, 60000.f);                          \
      asm volatile("" ::: "memory");                                           \
      buf ^= 1;                                                                \
    }
#else
#define F4(q, W_, k, acc)                                                      \
    acc = fmaf(q.x, W_[k], acc);     acc = fmaf(q.y, W_[k + 1], acc);          \
    acc = fmaf(q.z, W_[k + 2], acc); acc = fmaf(q.w, W_[k + 3], acc);

#define DSTEP(EC)                                                              \
    {                                                                          \
      const float4* pv = (const float4*)&psw[buf][h0];                         \
      const float4 q0 = pv[0], q1 = pv[1], q2 = pv[2], q3 = pv[3];             \
      const float4 q4 = pv[4], q5 = pv[5], q6 = pv[6], q7 = pv[7];             \
      const float P0 = psw[buf][0];                                            \
      float a0_ = 0.f, a1_ = 0.f, a2_ = 0.f, a3_ = 0.f;                        \
      float b0_ = 0.f, b1_ = 0.f, b2_ = 0.f, b3_ = 0.f;                        \
      F4(q0, WA, 0, a0_)  F4(q1, WA, 4, a1_)                                   \
      F4(q2, WA, 8, a2_)  F4(q3, WA, 12, a3_)                                  \
      F4(q4, WA, 16, a0_) F4(q5, WA, 20, a1_)                                  \
      F4(q6, WA, 24, a2_) F4(q7, WA, 28, a3_)                                  \
      F4(q0, WB, 0, b0_)  F4(q1, WB, 4, b1_)                                   \
      F4(q2, WB, 8, b2_)  F4(q3, WB, 12, b3_)                                  \
      F4(q4, WB, 16, b0_) F4(q5, WB, 20, b1_)                                  \
      F4(q6, WB, 24, b2_) F4(q7, WB, 28, b3_)                                  \
      const float SA = (a0_ + a1_) + (a2_ + a3_);                              \
      const float SB = (b0_ + b1_) + (b2_ + b3_);                              \
      const float S = SA + __shfl_xor(SB, 32);                                 \
      Pl = S * __builtin_amdgcn_rcpf(P0) * exp2f(fmaf((EC), L2E, -6.f));       \
      Csum += log2f(P0) + 6.f;                                                 \
      psw[buf ^ 1][i] = Pl;                                                    \
      asm volatile("" ::: "memory");                                           \
      buf ^= 1;                                                                \
    }
#endif

#define RUNPHASE(ts, te)                                                       \
    {                                                                          \
      int k_ = (ts);                                                           \
      float e0 = EML(k_), e1 = EML(k_ + 1), e2 = EML(k_ + 2), e3 = EML(k_ + 3);\
      for (; k_ + 4 <= (te); k_ += 4) {                                        \
        const float t0_ = e0, t1_ = e1, t2_ = e2, t3_ = e3;                    \
        e0 = EML(k_ + 4); DSTEP(t0_);                                          \
        e1 = EML(k_ + 5); DSTEP(t1_);                                          \
        e2 = EML(k_ + 6); DSTEP(t2_);                                          \
        e3 = EML(k_ + 7); DSTEP(t3_);                                          \
      }                                                                        \
      const int rem_ = (te) - k_;                                              \
      if (rem_ > 0) DSTEP(e0);                                                 \
      if (rem_ > 1) DSTEP(e1);                                                 \
      if (rem_ > 2) DSTEP(e2);                                                 \
    }

    float base = 0.f;
    if (s > 0) {
      RUNPHASE(t0 - WARM, t0);         // warm-up: direction converges
      base = Csum + log2f(wsum64(Pl)); // snapshot 1^T alpha at t0-1
    }
    RUNPHASE(t0, t0 + nmain);          // counted steps

    const float X = Csum + log2f(wsum64(Pl)) - base;
    if (i == 0) ws[WS_X + b * NSEG + s] = X;

#undef RUNPHASE
#undef DSTEP
#undef EML

  } else {
    // ================= numerator (R2-verified, log2 domain) =================
    const int b   = gw >> 1;
    const int dir = gw & 1;            // 0 = forward, 1 = backward
    const float* em = E + (size_t)b * TT * NN;
    const int l = lane;
    const bool v0 = (2 * l     <= 100);
    const bool v1 = (2 * l + 1 <= 100);
    const int k0 = v0 ? 2 * l     : 100;
    const int k1 = v1 ? 2 * l + 1 : 100;
    const int y0 = Y[b * LL + k0];
    const int y1 = Y[b * LL + k1];
    const float stw0 = TR[(y0 + 1) * NN + y0] * L2E;
    const float stw1 = TR[(y1 + 1) * NN + y1] * L2E;
    float aw0, aw1, b0, b1;
    if (dir == 0) {
      const int ym0 = Y[b * LL + (k0 > 0 ? k0 - 1 : 0)];
      aw0 = TR[(y0 + 1) * NN + ym0] * L2E;
      aw1 = TR[(y1 + 1) * NN + y0] * L2E;
      b0 = (k0 == 0) ? (TR[y0] + em[y0]) * L2E : NEG2;
      b1 = NEG2;
    } else {
      aw0 = TR[(y1 + 1) * NN + y0] * L2E;
      const int kp = (2 * l + 2 <= 100) ? 2 * l + 2 : 100;
      const int yp1 = Y[b * LL + kp];
      aw1 = TR[(yp1 + 1) * NN + y1] * L2E;
      b0 = em[(size_t)(TT - 1) * NN + y0] * L2E + ((k0 == 100) ? 0.f : NEG2);
      b1 = em[(size_t)(TT - 1) * NN + y1] * L2E + ((k1 == 100) ? 0.f : NEG2);
    }
    const bool pm0 = (dir == 0) ? (k0 > 0) : v1;
    const bool pm1 = (dir == 0) ? true : (2 * l + 2 <= 100);

#define NROW(s) ((size_t)((dir == 0) ? (s) : (TT - 1 - (s))) * NN)
#define NSTEP(EA, EB)                                                          \
    {                                                                          \
      const float ob0 = b0, ob1 = b1;                                          \
      const float nb = (dir == 0) ? __shfl_up(ob1, 1) : __shfl_down(ob0, 1);   \
      const float p0_ = pm0 ? ((dir == 0) ? nb : ob1) + aw0 : NEG2;            \
      const float p1_ = pm1 ? ((dir == 0) ? ob0 : nb) + aw1 : NEG2;            \
      const float x0 = ob0 + stw0, x1 = ob1 + stw1;                            \
      const float m0 = fmaxf(x0, p0_), m1 = fmaxf(x1, p1_);                    \
      b0 = m0 + log2f(exp2f(x0 - m0) + exp2f(p0_ - m0)) + (EA) * L2E;          \
      b1 = m1 + log2f(exp2f(x1 - m1) + exp2f(p1_ - m1)) + (EB) * L2E;          \
    }

    float ea0 = em[NROW(1) + y0], eb0 = em[NROW(1) + y1];
    float ea1 = em[NROW(2) + y0], eb1 = em[NROW(2) + y1];
    float ea2 = em[NROW(3) + y0], eb2 = em[NROW(3) + y1];
    float ea3 = em[NROW(4) + y0], eb3 = em[NROW(4) + y1];
    float ea4 = em[NROW(5) + y0], eb4 = em[NROW(5) + y1];
    float ea5 = em[NROW(6) + y0], eb5 = em[NROW(6) + y1];
    float ea6 = em[NROW(7) + y0], eb6 = em[NROW(7) + y1];
    float ea7 = em[NROW(8) + y0], eb7 = em[NROW(8) + y1];

    for (int it = 0; it < 249; ++it) {
      const int s = 1 + it * 8;
      const float ta0 = ea0, tb0 = eb0, ta1 = ea1, tb1 = eb1;
      const float ta2 = ea2, tb2 = eb2, ta3 = ea3, tb3 = eb3;
      const float ta4 = ea4, tb4 = eb4, ta5 = ea5, tb5 = eb5;
      const float ta6 = ea6, tb6 = eb6, ta7 = ea7, tb7 = eb7;
      ea0 = em[NROW(s + 8)  + y0]; eb0 = em[NROW(s + 8)  + y1]; NSTEP(ta0, tb0);
      ea1 = em[NROW(s + 9)  + y0]; eb1 = em[NROW(s + 9)  + y1]; NSTEP(ta1, tb1);
      ea2 = em[NROW(s + 10) + y0]; eb2 = em[NROW(s + 10) + y1]; NSTEP(ta2, tb2);
      ea3 = em[NROW(s + 11) + y0]; eb3 = em[NROW(s + 11) + y1]; NSTEP(ta3, tb3);
      ea4 = em[NROW(s + 12) + y0]; eb4 = em[NROW(s + 12) + y1]; NSTEP(ta4, tb4);
      ea5 = em[NROW(s + 13) + y0]; eb5 = em[NROW(s + 13) + y1]; NSTEP(ta5, tb5);
      ea6 = em[NROW(s + 14) + y0]; eb6 = em[NROW(s + 14) + y1]; NSTEP(ta6, tb6);
      ea7 = em[NROW(s + 15) + y0]; eb7 = em[NROW(s + 15) + y1]; NSTEP(ta7, tb7);
    }
    NSTEP(ea0, eb0); NSTEP(ea1, eb1); NSTEP(ea2, eb2); NSTEP(ea3, eb3);
    NSTEP(ea4, eb4); NSTEP(ea5, eb5); NSTEP(ea6, eb6);
#undef NSTEP
#undef NROW

    if (v0) ws[(dir ? WS_HB : WS_NF) + b * 112 + 2 * l]     = b0;
    if (v1) ws[(dir ? WS_HB : WS_NF) + b * 112 + 2 * l + 1] = b1;
  }
}

__global__ __launch_bounds__(128) void asg_combine(
    const float* __restrict__ TR, const int* __restrict__ Y,
    const float* __restrict__ ws, float* __restrict__ lossv)
{
  const int b = blockIdx.x;
  const int tid = threadIdx.x;
  __shared__ float sN[LL], sH[LL], red[128];
  __shared__ float sLogZ;

  if (tid == 0) {
    float z = 0.f;
    for (int s = 0; s < NSEG; ++s) z += ws[WS_X + b * NSEG + s];
    sLogZ = z;                              // log2(1^T alpha_{T-1}) = log2 Z
  }
  if (tid < LL) { sN[tid] = ws[WS_NF + b * 112 + tid]; sH[tid] = ws[WS_HB + b * 112 + tid]; }
  __syncthreads();

  // numerator bridge between fwd (t=1999) and bwd (t=2000)
  float val2 = -3.0e38f;
  if (tid < LL) {
    const int l = tid;
    const int y = Y[b * LL + l];
    const float s1 = sN[l] + TR[(y + 1) * NN + y] * L2E;
    float s2 = NEG2;
    if (l > 0) {
      const int ymm = Y[b * LL + l - 1];
      s2 = sN[l - 1] + TR[(y + 1) * NN + ymm] * L2E;
    }
    const float m = fmaxf(s1, s2);
    val2 = m + log2f(exp2f(s1 - m) + exp2f(s2 - m)) + sH[l];
  }
  red[tid] = val2;
  __syncthreads();
  if (tid == 0) {
    float m = red[0];
    for (int k = 1; k < LL; ++k) m = fmaxf(m, red[k]);
    float s = 0.f;
    for (int k = 0; k < LL; ++k) s += exp2f(red[k] - m);
    const float tgt2 = m + log2f(s);
    lossv[b] = (sLogZ - tgt2) * LN2F / (float)LL;
  }
}

__global__ __launch_bounds__(64) void asg_reduce(const float* __restrict__ lossv,
                                                 float* __restrict__ out)
{
  const int tid = threadIdx.x;
  float v = lossv[tid] + lossv[tid + 64];
  for (int off = 32; off; off >>= 1) v += __shfl_xor(v, off);
  if (tid == 0) out[0] = v * (1.0f / 128.0f);
}

extern "C" void kernel_launch(void* const* d_in, const int* in_sizes, int n_in,
                              void* d_out, int out_size, void* d_ws, size_t ws_size,
                              hipStream_t stream) {
  const float* E  = (const float*)d_in[0];
  const float* TR = (const float*)d_in[1];
  const int*   Y  = (const int*)d_in[2];
  float* out = (float*)d_out;
  float* ws  = (float*)d_ws;
  float* lossv = ws + WS_LOSS;

  // (NUMW + 128*NSEG) waves / 8 waves per block = 544 blocks
  asg_main<<<dim3((NUMW + 128 * NSEG) / 8), dim3(512), 0, stream>>>(E, TR, Y, ws);
  asg_combine<<<dim3(128), dim3(128), 0, stream>>>(TR, Y, ws, lossv);
  asg_reduce<<<dim3(1), dim3(64), 0, stream>>>(lossv, out);
}

// Round 6
// 272.953 us; speedup vs baseline: 1.8731x; 1.8731x over previous
//
#include <hip/hip_runtime.h>

// ASG loss, B=128 T=4000 N=64 L=101.
// R6: math identical to R4/R5 (both passed, absmax 0.0). Two perf fixes:
//  1) hot-loop exp2f/log2f -> raw v_exp_f32 / v_log_f32 builtins (the OCML
//     versions are multi-instruction and sit on the serial chains).
//  2) numerator waves de-clustered: one per block (blocks 0..255), so the
//     2000-step numerator chains never share a SIMD with each other.
// Denominator: overlap-and-discard segmented scan (NSEG=32, WARM=40),
// linear-space fdot2 matvec with per-step rescale, per-wave LDS slices.

#define TT 4000
#define NN 64
#define LL 101
#define NSEG 32
#define SEGN 125          // steps per segment (last segment: 124)
#define WARM 40

static constexpr float L2E  = 1.44269504088896340736f;   // log2(e)
static constexpr float LN2F = 0.69314718055994530942f;
static constexpr float NEG2 = -1.0e30f;

// ws layout (floats) - total ~132 KB
#define WS_X    0                      // [128][NSEG] per-segment log2 ratios
#define WS_NF   4096                   // [128][112] fwd numer (log2) at t=1999
#define WS_HB   18432                  // [128][112] bwd numer (log2) at t=2000
#define WS_LOSS 32768                  // [128] per-batch loss

#if defined(__has_builtin)
#if __has_builtin(__builtin_amdgcn_fdot2)
#define USE_FDOT2 1
#endif
#if __has_builtin(__builtin_amdgcn_exp2f)
#define FEXP2(x) __builtin_amdgcn_exp2f(x)
#endif
#if __has_builtin(__builtin_amdgcn_logf)
#define FLOG2(x) __builtin_amdgcn_logf(x)
#endif
#endif
#ifndef USE_FDOT2
#define USE_FDOT2 0
#endif
#ifndef FEXP2
#define FEXP2(x) exp2f(x)
#endif
#ifndef FLOG2
#define FLOG2(x) log2f(x)
#endif

typedef _Float16 h2 __attribute__((ext_vector_type(2)));

__device__ __forceinline__ float wsum64(float v) {
  v += __shfl_xor(v, 1);  v += __shfl_xor(v, 2);  v += __shfl_xor(v, 4);
  v += __shfl_xor(v, 8);  v += __shfl_xor(v, 16); v += __shfl_xor(v, 32);
  return v;
}

__global__ __launch_bounds__(512) void asg_main(
    const float* __restrict__ E, const float* __restrict__ TR,
    const int* __restrict__ Y, float* __restrict__ ws)
{
  const int bidx = blockIdx.x;
  const int w    = threadIdx.x >> 6;           // wave in block (0..7)
  const int lane = threadIdx.x & 63;
  const bool is_num = (bidx < 256) && (w == 0);

#if USE_FDOT2
  __shared__ _Float16 PS[8][2][64];            // per-wave slices
#else
  __shared__ float PS[8][2][64];
#endif

  if (!is_num) {
    // ================= denominator segment (1 wave) =================
    // wave -> segment index: blocks 0..255 contribute waves 1..7,
    // blocks 256..543 contribute waves 0..7.  4096 segments total.
    const int dw = (bidx < 256) ? (bidx * 7 + (w - 1))
                                : (1792 + (bidx - 256) * 8 + w);
    const int b  = dw >> 5;            // NSEG = 32
    const int s  = dw & 31;
    const float* em = E + (size_t)b * TT * NN;
    const int i = lane;
#if USE_FDOT2
    _Float16 (*psw)[64] = PS[w];
#else
    float (*psw)[64] = PS[w];
#endif

#if USE_FDOT2
    h2 W2[32];
#pragma unroll
    for (int k = 0; k < 32; ++k) {
      const float w0 = TR[(i + 1) * NN + 2 * k];
      const float w1 = TR[(i + 1) * NN + 2 * k + 1];
      h2 t; t.x = (_Float16)FEXP2(w0 * L2E); t.y = (_Float16)FEXP2(w1 * L2E);
      W2[k] = t;
    }
#else
    const int h0 = (i >> 5) << 5;      // pair-split: states {i, i^32}
    const int ip = i ^ 32;
    float WA[32], WB[32];
#pragma unroll
    for (int k = 0; k < 32; ++k) {
      const int j = h0 + k;
      WA[k] = FEXP2(TR[(i + 1) * NN + j] * L2E);
      WB[k] = FEXP2(TR[(ip + 1) * NN + j] * L2E);
    }
#endif

    const int t0    = 1 + SEGN * s;
    const int nmain = (s == NSEG - 1) ? (TT - t0) : SEGN;
    float Pl, Csum;
    if (s == 0) {
      const float a0  = (em[i] + TR[i]) * L2E;
      const float a00 = __shfl(a0, 0);
      Csum = a00;
      Pl   = FEXP2(a0 - a00);
    } else {
      Csum = 0.f;
      Pl   = 1.0f;
    }
#if USE_FDOT2
    psw[0][i] = (_Float16)Pl;
#else
    psw[0][i] = Pl;
#endif
    asm volatile("" ::: "memory");
    int buf = 0;

#define EML(t) em[(size_t)((t) < (TT - 1) ? (t) : (TT - 1)) * NN + i]

#if USE_FDOT2
#define BCH2(x) __builtin_bit_cast(h2, (x))
#define D4(u, k)                                                               \
    c0 = __builtin_amdgcn_fdot2(BCH2(u.x), W2[k], c0, false);                  \
    c1 = __builtin_amdgcn_fdot2(BCH2(u.y), W2[k + 1], c1, false);              \
    c2 = __builtin_amdgcn_fdot2(BCH2(u.z), W2[k + 2], c2, false);              \
    c3 = __builtin_amdgcn_fdot2(BCH2(u.w), W2[k + 3], c3, false);

#define DSTEP(EC)                                                              \
    {                                                                          \
      const uint4* pv = (const uint4*)&psw[buf][0];                            \
      const uint4 u0 = pv[0], u1 = pv[1], u2 = pv[2], u3 = pv[3];              \
      const uint4 u4 = pv[4], u5 = pv[5], u6 = pv[6], u7 = pv[7];              \
      float c0 = 0.f, c1 = 0.f, c2 = 0.f, c3 = 0.f;                            \
      D4(u0, 0)  D4(u1, 4)  D4(u2, 8)  D4(u3, 12)                              \
      D4(u4, 16) D4(u5, 20) D4(u6, 24) D4(u7, 28)                              \
      const float P0 = (float)BCH2(u0.x).x;                                    \
      const float S = (c0 + c1) + (c2 + c3);                                   \
      Pl = S * __builtin_amdgcn_rcpf(P0) * FEXP2(fmaf((EC), L2E, -6.f));       \
      Csum += FLOG2(P0) + 6.f;                                                 \
      psw[buf ^ 1][i] = (_Float16)fminf(Pl, 60000.f);                          \
      asm volatile("" ::: "memory");                                           \
      buf ^= 1;                                                                \
    }
#else
#define F4(q, W_, k, acc)                                                      \
    acc = fmaf(q.x, W_[k], acc);     acc = fmaf(q.y, W_[k + 1], acc);          \
    acc = fmaf(q.z, W_[k + 2], acc); acc = fmaf(q.w, W_[k + 3], acc);

#define DSTEP(EC)                                                              \
    {                                                                          \
      const float4* pv = (const float4*)&psw[buf][h0];                         \
      const float4 q0 = pv[0], q1 = pv[1], q2 = pv[2], q3 = pv[3];             \
      const float4 q4 = pv[4], q5 = pv[5], q6 = pv[6], q7 = pv[7];             \
      const float P0 = psw[buf][0];                                            \
      float a0_ = 0.f, a1_ = 0.f, a2_ = 0.f, a3_ = 0.f;                        \
      float b0_ = 0.f, b1_ = 0.f, b2_ = 0.f, b3_ = 0.f;                        \
      F4(q0, WA, 0, a0_)  F4(q1, WA, 4, a1_)                                   \
      F4(q2, WA, 8, a2_)  F4(q3, WA, 12, a3_)                                  \
      F4(q4, WA, 16, a0_) F4(q5, WA, 20, a1_)                                  \
      F4(q6, WA, 24, a2_) F4(q7, WA, 28, a3_)                                  \
      F4(q0, WB, 0, b0_)  F4(q1, WB, 4, b1_)                                   \
      F4(q2, WB, 8, b2_)  F4(q3, WB, 12, b3_)                                  \
      F4(q4, WB, 16, b0_) F4(q5, WB, 20, b1_)                                  \
      F4(q6, WB, 24, b2_) F4(q7, WB, 28, b3_)                                  \
      const float SA = (a0_ + a1_) + (a2_ + a3_);                              \
      const float SB = (b0_ + b1_) + (b2_ + b3_);                              \
      const float S = SA + __shfl_xor(SB, 32);                                 \
      Pl = S * __builtin_amdgcn_rcpf(P0) * FEXP2(fmaf((EC), L2E, -6.f));       \
      Csum += FLOG2(P0) + 6.f;                                                 \
      psw[buf ^ 1][i] = Pl;                                                    \
      asm volatile("" ::: "memory");                                           \
      buf ^= 1;                                                                \
    }
#endif

#define RUNPHASE(ts, te)                                                       \
    {                                                                          \
      int k_ = (ts);                                                           \
      float e0 = EML(k_), e1 = EML(k_ + 1), e2 = EML(k_ + 2), e3 = EML(k_ + 3);\
      for (; k_ + 4 <= (te); k_ += 4) {                                        \
        const float t0_ = e0, t1_ = e1, t2_ = e2, t3_ = e3;                    \
        e0 = EML(k_ + 4); DSTEP(t0_);                                          \
        e1 = EML(k_ + 5); DSTEP(t1_);                                          \
        e2 = EML(k_ + 6); DSTEP(t2_);                                          \
        e3 = EML(k_ + 7); DSTEP(t3_);                                          \
      }                                                                        \
      const int rem_ = (te) - k_;                                              \
      if (rem_ > 0) DSTEP(e0);                                                 \
      if (rem_ > 1) DSTEP(e1);                                                 \
      if (rem_ > 2) DSTEP(e2);                                                 \
    }

    float base = 0.f;
    if (s > 0) {
      RUNPHASE(t0 - WARM, t0);         // warm-up: direction converges
      base = Csum + FLOG2(wsum64(Pl)); // snapshot 1^T alpha at t0-1
    }
    RUNPHASE(t0, t0 + nmain);          // counted steps

    const float X = Csum + FLOG2(wsum64(Pl)) - base;
    if (i == 0) ws[WS_X + b * NSEG + s] = X;

#undef RUNPHASE
#undef DSTEP
#undef EML

  } else {
    // ================= numerator (log2 domain, native exp/log) ============
    const int b   = bidx >> 1;
    const int dir = bidx & 1;          // 0 = forward, 1 = backward
    const float* em = E + (size_t)b * TT * NN;
    const int l = lane;
    const bool v0 = (2 * l     <= 100);
    const bool v1 = (2 * l + 1 <= 100);
    const int k0 = v0 ? 2 * l     : 100;
    const int k1 = v1 ? 2 * l + 1 : 100;
    const int y0 = Y[b * LL + k0];
    const int y1 = Y[b * LL + k1];
    const float stw0 = TR[(y0 + 1) * NN + y0] * L2E;
    const float stw1 = TR[(y1 + 1) * NN + y1] * L2E;
    float aw0, aw1, b0, b1;
    if (dir == 0) {
      const int ym0 = Y[b * LL + (k0 > 0 ? k0 - 1 : 0)];
      aw0 = TR[(y0 + 1) * NN + ym0] * L2E;
      aw1 = TR[(y1 + 1) * NN + y0] * L2E;
      b0 = (k0 == 0) ? (TR[y0] + em[y0]) * L2E : NEG2;
      b1 = NEG2;
    } else {
      aw0 = TR[(y1 + 1) * NN + y0] * L2E;
      const int kp = (2 * l + 2 <= 100) ? 2 * l + 2 : 100;
      const int yp1 = Y[b * LL + kp];
      aw1 = TR[(yp1 + 1) * NN + y1] * L2E;
      b0 = em[(size_t)(TT - 1) * NN + y0] * L2E + ((k0 == 100) ? 0.f : NEG2);
      b1 = em[(size_t)(TT - 1) * NN + y1] * L2E + ((k1 == 100) ? 0.f : NEG2);
    }
    const bool pm0 = (dir == 0) ? (k0 > 0) : v1;
    const bool pm1 = (dir == 0) ? true : (2 * l + 2 <= 100);

#define NROW(s) ((size_t)((dir == 0) ? (s) : (TT - 1 - (s))) * NN)
#define NSTEP(EA, EB)                                                          \
    {                                                                          \
      const float ob0 = b0, ob1 = b1;                                          \
      const float nb = (dir == 0) ? __shfl_up(ob1, 1) : __shfl_down(ob0, 1);   \
      const float p0_ = pm0 ? ((dir == 0) ? nb : ob1) + aw0 : NEG2;            \
      const float p1_ = pm1 ? ((dir == 0) ? ob0 : nb) + aw1 : NEG2;            \
      const float x0 = ob0 + stw0, x1 = ob1 + stw1;                            \
      const float m0 = fmaxf(x0, p0_), m1 = fmaxf(x1, p1_);                    \
      b0 = m0 + FLOG2(FEXP2(x0 - m0) + FEXP2(p0_ - m0)) + (EA) * L2E;          \
      b1 = m1 + FLOG2(FEXP2(x1 - m1) + FEXP2(p1_ - m1)) + (EB) * L2E;          \
    }

    float ea0 = em[NROW(1) + y0], eb0 = em[NROW(1) + y1];
    float ea1 = em[NROW(2) + y0], eb1 = em[NROW(2) + y1];
    float ea2 = em[NROW(3) + y0], eb2 = em[NROW(3) + y1];
    float ea3 = em[NROW(4) + y0], eb3 = em[NROW(4) + y1];
    float ea4 = em[NROW(5) + y0], eb4 = em[NROW(5) + y1];
    float ea5 = em[NROW(6) + y0], eb5 = em[NROW(6) + y1];
    float ea6 = em[NROW(7) + y0], eb6 = em[NROW(7) + y1];
    float ea7 = em[NROW(8) + y0], eb7 = em[NROW(8) + y1];

    for (int it = 0; it < 249; ++it) {
      const int s = 1 + it * 8;
      const float ta0 = ea0, tb0 = eb0, ta1 = ea1, tb1 = eb1;
      const float ta2 = ea2, tb2 = eb2, ta3 = ea3, tb3 = eb3;
      const float ta4 = ea4, tb4 = eb4, ta5 = ea5, tb5 = eb5;
      const float ta6 = ea6, tb6 = eb6, ta7 = ea7, tb7 = eb7;
      ea0 = em[NROW(s + 8)  + y0]; eb0 = em[NROW(s + 8)  + y1]; NSTEP(ta0, tb0);
      ea1 = em[NROW(s + 9)  + y0]; eb1 = em[NROW(s + 9)  + y1]; NSTEP(ta1, tb1);
      ea2 = em[NROW(s + 10) + y0]; eb2 = em[NROW(s + 10) + y1]; NSTEP(ta2, tb2);
      ea3 = em[NROW(s + 11) + y0]; eb3 = em[NROW(s + 11) + y1]; NSTEP(ta3, tb3);
      ea4 = em[NROW(s + 12) + y0]; eb4 = em[NROW(s + 12) + y1]; NSTEP(ta4, tb4);
      ea5 = em[NROW(s + 13) + y0]; eb5 = em[NROW(s + 13) + y1]; NSTEP(ta5, tb5);
      ea6 = em[NROW(s + 14) + y0]; eb6 = em[NROW(s + 14) + y1]; NSTEP(ta6, tb6);
      ea7 = em[NROW(s + 15) + y0]; eb7 = em[NROW(s + 15) + y1]; NSTEP(ta7, tb7);
    }
    NSTEP(ea0, eb0); NSTEP(ea1, eb1); NSTEP(ea2, eb2); NSTEP(ea3, eb3);
    NSTEP(ea4, eb4); NSTEP(ea5, eb5); NSTEP(ea6, eb6);
#undef NSTEP
#undef NROW

    if (v0) ws[(dir ? WS_HB : WS_NF) + b * 112 + 2 * l]     = b0;
    if (v1) ws[(dir ? WS_HB : WS_NF) + b * 112 + 2 * l + 1] = b1;
  }
}

__global__ __launch_bounds__(128) void asg_combine(
    const float* __restrict__ TR, const int* __restrict__ Y,
    const float* __restrict__ ws, float* __restrict__ lossv)
{
  const int b = blockIdx.x;
  const int tid = threadIdx.x;
  __shared__ float sN[LL], sH[LL], red[128];
  __shared__ float sLogZ;

  if (tid == 0) {
    float z = 0.f;
    for (int s = 0; s < NSEG; ++s) z += ws[WS_X + b * NSEG + s];
    sLogZ = z;                              // log2(1^T alpha_{T-1}) = log2 Z
  }
  if (tid < LL) { sN[tid] = ws[WS_NF + b * 112 + tid]; sH[tid] = ws[WS_HB + b * 112 + tid]; }
  __syncthreads();

  // numerator bridge between fwd (t=1999) and bwd (t=2000)
  float val2 = -3.0e38f;
  if (tid < LL) {
    const int l = tid;
    const int y = Y[b * LL + l];
    const float s1 = sN[l] + TR[(y + 1) * NN + y] * L2E;
    float s2 = NEG2;
    if (l > 0) {
      const int ymm = Y[b * LL + l - 1];
      s2 = sN[l - 1] + TR[(y + 1) * NN + ymm] * L2E;
    }
    const float m = fmaxf(s1, s2);
    val2 = m + log2f(exp2f(s1 - m) + exp2f(s2 - m)) + sH[l];
  }
  red[tid] = val2;
  __syncthreads();
  if (tid == 0) {
    float m = red[0];
    for (int k = 1; k < LL; ++k) m = fmaxf(m, red[k]);
    float s = 0.f;
    for (int k = 0; k < LL; ++k) s += exp2f(red[k] - m);
    const float tgt2 = m + log2f(s);
    lossv[b] = (sLogZ - tgt2) * LN2F / (float)LL;
  }
}

__global__ __launch_bounds__(64) void asg_reduce(const float* __restrict__ lossv,
                                                 float* __restrict__ out)
{
  const int tid = threadIdx.x;
  float v = lossv[tid] + lossv[tid + 64];
  for (int off = 32; off; off >>= 1) v += __shfl_xor(v, off);
  if (tid == 0) out[0] = v * (1.0f / 128.0f);
}

extern "C" void kernel_launch(void* const* d_in, const int* in_sizes, int n_in,
                              void* d_out, int out_size, void* d_ws, size_t ws_size,
                              hipStream_t stream) {
  const float* E  = (const float*)d_in[0];
  const float* TR = (const float*)d_in[1];
  const int*   Y  = (const int*)d_in[2];
  float* out = (float*)d_out;
  float* ws  = (float*)d_ws;
  float* lossv = ws + WS_LOSS;

  // 544 blocks x 8 waves: 256 numerator waves (one per block, blocks 0..255)
  // + 4096 denominator segment waves.
  asg_main<<<dim3(544), dim3(512), 0, stream>>>(E, TR, Y, ws);
  asg_combine<<<dim3(128), dim3(128), 0, stream>>>(TR, Y, ws, lossv);
  asg_reduce<<<dim3(1), dim3(64), 0, stream>>>(lossv, out);
}

// Round 7
// 174.650 us; speedup vs baseline: 2.9274x; 1.5629x over previous
//
#include <hip/hip_runtime.h>

// ASG loss, B=128 T=4000 N=64 L=101.
// R7: denominator unchanged from R6 (passed, absmax 0.0).
// Numerator rewritten: linear-space per-lane-scaled recurrence.
//   B represents 2^(beta - C) per lane; per step two fma+mul updates;
//   neighbor value moved by DPP wave_shr:1 / wave_shl:1 (VALU, no LDS pipe).
//   Per-lane rescale every 8 steps (exponent extract); neighbor scale
//   mismatch folded into ADJ = 2^(C_nbr - C) * w_recv, constant per epoch.
//   Emissions prefetched 2 epochs (16 steps) deep.

#define TT 4000
#define NN 64
#define LL 101
#define NSEG 32
#define SEGN 125          // steps per segment (last segment: 124)
#define WARM 40

static constexpr float L2E  = 1.44269504088896340736f;   // log2(e)
static constexpr float LN2F = 0.69314718055994530942f;
static constexpr float NEG2 = -1.0e30f;

// ws layout (floats) - total ~132 KB
#define WS_X    0                      // [128][NSEG] per-segment log2 ratios
#define WS_NF   4096                   // [128][112] fwd numer (log2) at t=1999
#define WS_HB   18432                  // [128][112] bwd numer (log2) at t=2000
#define WS_LOSS 32768                  // [128] per-batch loss

#if defined(__has_builtin)
#if __has_builtin(__builtin_amdgcn_fdot2)
#define USE_FDOT2 1
#endif
#if __has_builtin(__builtin_amdgcn_exp2f)
#define FEXP2(x) __builtin_amdgcn_exp2f(x)
#endif
#if __has_builtin(__builtin_amdgcn_logf)
#define FLOG2(x) __builtin_amdgcn_logf(x)
#endif
#endif
#ifndef USE_FDOT2
#define USE_FDOT2 0
#endif
#ifndef FEXP2
#define FEXP2(x) exp2f(x)
#endif
#ifndef FLOG2
#define FLOG2(x) log2f(x)
#endif

typedef _Float16 h2 __attribute__((ext_vector_type(2)));

__device__ __forceinline__ float wsum64(float v) {
  v += __shfl_xor(v, 1);  v += __shfl_xor(v, 2);  v += __shfl_xor(v, 4);
  v += __shfl_xor(v, 8);  v += __shfl_xor(v, 16); v += __shfl_xor(v, 32);
  return v;
}

// DPP lane shift across the whole 64-wave: 0x138 = wave_shr:1 (lane i <- i-1),
// 0x130 = wave_shl:1 (lane i <- i+1). Invalid boundary lanes read 0.
template<int CTRL>
__device__ __forceinline__ float dppf(float x) {
  return __builtin_bit_cast(float, __builtin_amdgcn_update_dpp(
      0, __builtin_bit_cast(int, x), CTRL, 0xf, 0xf, true));
}

// ---------------- numerator chain (linear space, DPP neighbor) -------------
template<int DIR>
__device__ __forceinline__ void num_chain(const float* __restrict__ em,
                                          const float* __restrict__ TR,
                                          const int* __restrict__ Y,
                                          float* __restrict__ ws,
                                          const int b, const int l)
{
  const bool v0 = (2 * l     <= 100);
  const bool v1 = (2 * l + 1 <= 100);
  const int k0 = v0 ? 2 * l     : 100;
  const int k1 = v1 ? 2 * l + 1 : 100;
  const int y0 = Y[b * LL + k0];
  const int y1 = Y[b * LL + k1];
  const float SW0 = v0 ? FEXP2(TR[(y0 + 1) * NN + y0] * L2E) : 0.f;
  const float SW1 = v1 ? FEXP2(TR[(y1 + 1) * NN + y1] * L2E) : 0.f;
  float WLOC, WRECV, B0, B1, C;
  bool recvok;
  if (DIR == 0) {
    WLOC = v1 ? FEXP2(TR[(y1 + 1) * NN + y0] * L2E) : 0.f;       // k0 -> k1
    const int ym0 = Y[b * LL + (k0 > 0 ? k0 - 1 : 0)];
    recvok = v0 && (l > 0);
    WRECV = recvok ? FEXP2(TR[(y0 + 1) * NN + ym0] * L2E) : 0.f; // k0-1 -> k0
    B0 = (l == 0) ? 1.f : 0.f;
    B1 = 0.f;
    C  = (l == 0) ? (TR[y0] + em[y0]) * L2E : 0.f;
  } else {
    WLOC = v1 ? FEXP2(TR[(y1 + 1) * NN + y0] * L2E) : 0.f;       // k0 -> k1
    const int kp = (2 * l + 2 <= 100) ? 2 * l + 2 : 100;
    const int yp1 = Y[b * LL + kp];
    recvok = (2 * l + 2 <= 100);
    WRECV = recvok ? FEXP2(TR[(yp1 + 1) * NN + y1] * L2E) : 0.f; // k1 -> k1+1
    B0 = (l == 50) ? 1.f : 0.f;
    B1 = 0.f;
    C  = (l == 50) ? em[(size_t)(TT - 1) * NN + y0] * L2E : 0.f;
  }

#define TROW(t) ((size_t)((DIR == 0) ? (t) : (TT - 1 - (t))) * NN)

  float ca[8], cb[8], na[8], nb[8];
#pragma unroll
  for (int k = 0; k < 8; ++k) {                  // epoch 0: t = 1..8
    ca[k] = em[TROW(1 + k) + y0];
    cb[k] = em[TROW(1 + k) + y1];
  }
#pragma unroll
  for (int k = 0; k < 8; ++k) {                  // epoch 1: t = 9..16
    na[k] = em[TROW(9 + k) + y0];
    nb[k] = em[TROW(9 + k) + y1];
  }

  float ADJ = 0.f;

#define RESCALE()                                                              \
  {                                                                            \
    const float v = B0 + B1;                                                   \
    const int bits = __builtin_bit_cast(int, v);                               \
    const int m = (v > 0.f) ? ((bits >> 23) & 255) - 127 : 0;                  \
    const float sc = __builtin_bit_cast(float, (127 - m) << 23);               \
    B0 *= sc; B1 *= sc; C += (float)m;                                         \
    const float Cn = dppf<(DIR == 0) ? 0x138 : 0x130>(C);                      \
    const float dC = fminf(fmaxf(Cn - C, -120.f), 120.f);                      \
    ADJ = recvok ? FEXP2(dC) * WRECV : 0.f;                                    \
  }

#define NSTEP(EA, EB)                                                          \
  {                                                                            \
    const float E0 = FEXP2((EA) * L2E);                                        \
    const float E1 = FEXP2((EB) * L2E);                                        \
    if (DIR == 0) {                                                            \
      const float NB = dppf<0x138>(B1);                                        \
      const float t0 = fmaf(NB, ADJ, B0 * SW0);                                \
      const float t1 = fmaf(B0, WLOC, B1 * SW1);                               \
      B0 = t0 * E0; B1 = t1 * E1;                                              \
    } else {                                                                   \
      const float NB = dppf<0x130>(B0);                                        \
      const float t1 = fmaf(NB, ADJ, B1 * SW1);                                \
      const float t0 = fmaf(B1, WLOC, B0 * SW0);                               \
      B0 = t0 * E0; B1 = t1 * E1;                                              \
    }                                                                          \
  }

  // main: 249 epochs x 8 steps = t 1..1992
  for (int ep = 0; ep < 249; ++ep) {
    RESCALE();
    float pa[8], pb[8];
#pragma unroll
    for (int k = 0; k < 8; ++k) {                // prefetch epoch ep+2
      int t = 17 + 8 * ep + k;
      t = (t < 1999) ? t : 1999;
      pa[k] = em[TROW(t) + y0];
      pb[k] = em[TROW(t) + y1];
    }
#pragma unroll
    for (int k = 0; k < 8; ++k) NSTEP(ca[k], cb[k]);
#pragma unroll
    for (int k = 0; k < 8; ++k) { ca[k] = na[k]; cb[k] = nb[k];
                                  na[k] = pa[k]; nb[k] = pb[k]; }
  }
  // tail: t = 1993..1999 (7 steps)
  RESCALE();
#pragma unroll
  for (int k = 0; k < 7; ++k) NSTEP(ca[k], cb[k]);

#undef NSTEP
#undef RESCALE
#undef TROW

  const float o0 = (B0 > 1e-37f) ? C + FLOG2(B0) : NEG2;
  const float o1 = (B1 > 1e-37f) ? C + FLOG2(B1) : NEG2;
  const int base = (DIR ? WS_HB : WS_NF) + b * 112;
  if (v0) ws[base + 2 * l]     = o0;
  if (v1) ws[base + 2 * l + 1] = o1;
}

__global__ __launch_bounds__(512) void asg_main(
    const float* __restrict__ E, const float* __restrict__ TR,
    const int* __restrict__ Y, float* __restrict__ ws)
{
  const int bidx = blockIdx.x;
  const int w    = threadIdx.x >> 6;           // wave in block (0..7)
  const int lane = threadIdx.x & 63;
  const bool is_num = (bidx < 256) && (w == 0);

#if USE_FDOT2
  __shared__ _Float16 PS[8][2][64];            // per-wave slices
#else
  __shared__ float PS[8][2][64];
#endif

  if (!is_num) {
    // ================= denominator segment (1 wave) — R6 verbatim ========
    const int dw = (bidx < 256) ? (bidx * 7 + (w - 1))
                                : (1792 + (bidx - 256) * 8 + w);
    const int b  = dw >> 5;            // NSEG = 32
    const int s  = dw & 31;
    const float* em = E + (size_t)b * TT * NN;
    const int i = lane;
#if USE_FDOT2
    _Float16 (*psw)[64] = PS[w];
#else
    float (*psw)[64] = PS[w];
#endif

#if USE_FDOT2
    h2 W2[32];
#pragma unroll
    for (int k = 0; k < 32; ++k) {
      const float w0 = TR[(i + 1) * NN + 2 * k];
      const float w1 = TR[(i + 1) * NN + 2 * k + 1];
      h2 t; t.x = (_Float16)FEXP2(w0 * L2E); t.y = (_Float16)FEXP2(w1 * L2E);
      W2[k] = t;
    }
#else
    const int h0 = (i >> 5) << 5;      // pair-split: states {i, i^32}
    const int ip = i ^ 32;
    float WA[32], WB[32];
#pragma unroll
    for (int k = 0; k < 32; ++k) {
      const int j = h0 + k;
      WA[k] = FEXP2(TR[(i + 1) * NN + j] * L2E);
      WB[k] = FEXP2(TR[(ip + 1) * NN + j] * L2E);
    }
#endif

    const int t0    = 1 + SEGN * s;
    const int nmain = (s == NSEG - 1) ? (TT - t0) : SEGN;
    float Pl, Csum;
    if (s == 0) {
      const float a0  = (em[i] + TR[i]) * L2E;
      const float a00 = __shfl(a0, 0);
      Csum = a00;
      Pl   = FEXP2(a0 - a00);
    } else {
      Csum = 0.f;
      Pl   = 1.0f;
    }
#if USE_FDOT2
    psw[0][i] = (_Float16)Pl;
#else
    psw[0][i] = Pl;
#endif
    asm volatile("" ::: "memory");
    int buf = 0;

#define EML(t) em[(size_t)((t) < (TT - 1) ? (t) : (TT - 1)) * NN + i]

#if USE_FDOT2
#define BCH2(x) __builtin_bit_cast(h2, (x))
#define D4(u, k)                                                               \
    c0 = __builtin_amdgcn_fdot2(BCH2(u.x), W2[k], c0, false);                  \
    c1 = __builtin_amdgcn_fdot2(BCH2(u.y), W2[k + 1], c1, false);              \
    c2 = __builtin_amdgcn_fdot2(BCH2(u.z), W2[k + 2], c2, false);              \
    c3 = __builtin_amdgcn_fdot2(BCH2(u.w), W2[k + 3], c3, false);

#define DSTEP(EC)                                                              \
    {                                                                          \
      const uint4* pv = (const uint4*)&psw[buf][0];                            \
      const uint4 u0 = pv[0], u1 = pv[1], u2 = pv[2], u3 = pv[3];              \
      const uint4 u4 = pv[4], u5 = pv[5], u6 = pv[6], u7 = pv[7];              \
      float c0 = 0.f, c1 = 0.f, c2 = 0.f, c3 = 0.f;                            \
      D4(u0, 0)  D4(u1, 4)  D4(u2, 8)  D4(u3, 12)                              \
      D4(u4, 16) D4(u5, 20) D4(u6, 24) D4(u7, 28)                              \
      const float P0 = (float)BCH2(u0.x).x;                                    \
      const float S = (c0 + c1) + (c2 + c3);                                   \
      Pl = S * __builtin_amdgcn_rcpf(P0) * FEXP2(fmaf((EC), L2E, -6.f));       \
      Csum += FLOG2(P0) + 6.f;                                                 \
      psw[buf ^ 1][i] = (_Float16)fminf(Pl, 60000.f);                          \
      asm volatile("" ::: "memory");                                           \
      buf ^= 1;                                                                \
    }
#else
#define F4(q, W_, k, acc)                                                      \
    acc = fmaf(q.x, W_[k], acc);     acc = fmaf(q.y, W_[k + 1], acc);          \
    acc = fmaf(q.z, W_[k + 2], acc); acc = fmaf(q.w, W_[k + 3], acc);

#define DSTEP(EC)                                                              \
    {                                                                          \
      const float4* pv = (const float4*)&psw[buf][h0];                         \
      const float4 q0 = pv[0], q1 = pv[1], q2 = pv[2], q3 = pv[3];             \
      const float4 q4 = pv[4], q5 = pv[5], q6 = pv[6], q7 = pv[7];             \
      const float P0 = psw[buf][0];                                            \
      float a0_ = 0.f, a1_ = 0.f, a2_ = 0.f, a3_ = 0.f;                        \
      float b0_ = 0.f, b1_ = 0.f, b2_ = 0.f, b3_ = 0.f;                        \
      F4(q0, WA, 0, a0_)  F4(q1, WA, 4, a1_)                                   \
      F4(q2, WA, 8, a2_)  F4(q3, WA, 12, a3_)                                  \
      F4(q4, WA, 16, a0_) F4(q5, WA, 20, a1_)                                  \
      F4(q6, WA, 24, a2_) F4(q7, WA, 28, a3_)                                  \
      F4(q0, WB, 0, b0_)  F4(q1, WB, 4, b1_)                                   \
      F4(q2, WB, 8, b2_)  F4(q3, WB, 12, b3_)                                  \
      F4(q4, WB, 16, b0_) F4(q5, WB, 20, b1_)                                  \
      F4(q6, WB, 24, b2_) F4(q7, WB, 28, b3_)                                  \
      const float SA = (a0_ + a1_) + (a2_ + a3_);                              \
      const float SB = (b0_ + b1_) + (b2_ + b3_);                              \
      const float S = SA + __shfl_xor(SB, 32);                                 \
      Pl = S * __builtin_amdgcn_rcpf(P0) * FEXP2(fmaf((EC), L2E, -6.f));       \
      Csum += FLOG2(P0) + 6.f;                                                 \
      psw[buf ^ 1][i] = Pl;                                                    \
      asm volatile("" ::: "memory");                                           \
      buf ^= 1;                                                                \
    }
#endif

#define RUNPHASE(ts, te)                                                       \
    {                                                                          \
      int k_ = (ts);                                                           \
      float e0 = EML(k_), e1 = EML(k_ + 1), e2 = EML(k_ + 2), e3 = EML(k_ + 3);\
      for (; k_ + 4 <= (te); k_ += 4) {                                        \
        const float t0_ = e0, t1_ = e1, t2_ = e2, t3_ = e3;                    \
        e0 = EML(k_ + 4); DSTEP(t0_);                                          \
        e1 = EML(k_ + 5); DSTEP(t1_);                                          \
        e2 = EML(k_ + 6); DSTEP(t2_);                                          \
        e3 = EML(k_ + 7); DSTEP(t3_);                                          \
      }                                                                        \
      const int rem_ = (te) - k_;                                              \
      if (rem_ > 0) DSTEP(e0);                                                 \
      if (rem_ > 1) DSTEP(e1);                                                 \
      if (rem_ > 2) DSTEP(e2);                                                 \
    }

    float base = 0.f;
    if (s > 0) {
      RUNPHASE(t0 - WARM, t0);         // warm-up: direction converges
      base = Csum + FLOG2(wsum64(Pl)); // snapshot 1^T alpha at t0-1
    }
    RUNPHASE(t0, t0 + nmain);          // counted steps

    const float X = Csum + FLOG2(wsum64(Pl)) - base;
    if (i == 0) ws[WS_X + b * NSEG + s] = X;

#undef RUNPHASE
#undef DSTEP
#undef EML

  } else {
    // ================= numerator (linear space, DPP) ======================
    const int b   = bidx >> 1;
    const int dir = bidx & 1;          // 0 = forward, 1 = backward
    const float* em = E + (size_t)b * TT * NN;
    if (dir == 0) num_chain<0>(em, TR, Y, ws, b, lane);
    else          num_chain<1>(em, TR, Y, ws, b, lane);
  }
}

__global__ __launch_bounds__(128) void asg_combine(
    const float* __restrict__ TR, const int* __restrict__ Y,
    const float* __restrict__ ws, float* __restrict__ lossv)
{
  const int b = blockIdx.x;
  const int tid = threadIdx.x;
  __shared__ float sN[LL], sH[LL], red[128];
  __shared__ float sLogZ;

  if (tid == 0) {
    float z = 0.f;
    for (int s = 0; s < NSEG; ++s) z += ws[WS_X + b * NSEG + s];
    sLogZ = z;                              // log2(1^T alpha_{T-1}) = log2 Z
  }
  if (tid < LL) { sN[tid] = ws[WS_NF + b * 112 + tid]; sH[tid] = ws[WS_HB + b * 112 + tid]; }
  __syncthreads();

  // numerator bridge between fwd (t=1999) and bwd (t=2000)
  float val2 = -3.0e38f;
  if (tid < LL) {
    const int l = tid;
    const int y = Y[b * LL + l];
    const float s1 = sN[l] + TR[(y + 1) * NN + y] * L2E;
    float s2 = NEG2;
    if (l > 0) {
      const int ymm = Y[b * LL + l - 1];
      s2 = sN[l - 1] + TR[(y + 1) * NN + ymm] * L2E;
    }
    const float m = fmaxf(s1, s2);
    val2 = m + log2f(exp2f(s1 - m) + exp2f(s2 - m)) + sH[l];
  }
  red[tid] = val2;
  __syncthreads();
  if (tid == 0) {
    float m = red[0];
    for (int k = 1; k < LL; ++k) m = fmaxf(m, red[k]);
    float s = 0.f;
    for (int k = 0; k < LL; ++k) s += exp2f(red[k] - m);
    const float tgt2 = m + log2f(s);
    lossv[b] = (sLogZ - tgt2) * LN2F / (float)LL;
  }
}

__global__ __launch_bounds__(64) void asg_reduce(const float* __restrict__ lossv,
                                                 float* __restrict__ out)
{
  const int tid = threadIdx.x;
  float v = lossv[tid] + lossv[tid + 64];
  for (int off = 32; off; off >>= 1) v += __shfl_xor(v, off);
  if (tid == 0) out[0] = v * (1.0f / 128.0f);
}

extern "C" void kernel_launch(void* const* d_in, const int* in_sizes, int n_in,
                              void* d_out, int out_size, void* d_ws, size_t ws_size,
                              hipStream_t stream) {
  const float* E  = (const float*)d_in[0];
  const float* TR = (const float*)d_in[1];
  const int*   Y  = (const int*)d_in[2];
  float* out = (float*)d_out;
  float* ws  = (float*)d_ws;
  float* lossv = ws + WS_LOSS;

  // 544 blocks x 8 waves: 256 numerator waves (one per block, blocks 0..255)
  // + 4096 denominator segment waves.
  asg_main<<<dim3(544), dim3(512), 0, stream>>>(E, TR, Y, ws);
  asg_combine<<<dim3(128), dim3(128), 0, stream>>>(TR, Y, ws, lossv);
  asg_reduce<<<dim3(1), dim3(64), 0, stream>>>(lossv, out);
}

// Round 10
// 127.095 us; speedup vs baseline: 4.0228x; 1.3742x over previous
//
#include <hip/hip_runtime.h>

// ASG loss, B=128 T=4000 N=64 L=101.
// R10: R9 + Csum bookkeeping fix.
//   R9's finite error (184.3 == reference loss magnitude) isolated the bug:
//   STEP downscales P by 2^-6.7 per step (folded into the emission exp2) but
//   the -6.7/step was never added back to the log accumulator. Fix: add
//   +6.7*steps to the snapshot (31 steps) and final (155 steps) readouts.
//   Telescoping: 6.7*(155 + 31*124) = 6.7*3999 = total offset over t=1..3999.
//   MFMA fragment-layout identity (C/D == B operand) is validated by R9's
//   exact-explainable error. Everything else identical to R9.
// Numerator: R7 verbatim (linear-space DPP chains), wave 1 of each block.

#define TT 4000
#define NN 64
#define LL 101
#define NSEG 32

static constexpr float L2E  = 1.44269504088896340736f;   // log2(e)
static constexpr float LN2F = 0.69314718055994530942f;
static constexpr float NEG2 = -1.0e30f;

// ws layout (floats)
#define WS_X    0                      // [128][NSEG] per-segment log2 ratios
#define WS_NF   4096                   // [128][112] fwd numer (log2)
#define WS_HB   18432                  // [128][112] bwd numer (log2)
#define WS_LOSS 32768                  // [128] per-batch loss

#if defined(__has_builtin)
#if __has_builtin(__builtin_amdgcn_mfma_f32_16x16x16bf16_1k)
#define BF16MM 1
#endif
#if __has_builtin(__builtin_amdgcn_exp2f)
#define FEXP2(x) __builtin_amdgcn_exp2f(x)
#endif
#if __has_builtin(__builtin_amdgcn_logf)
#define FLOG2(x) __builtin_amdgcn_logf(x)
#endif
#endif
#ifndef FEXP2
#define FEXP2(x) exp2f(x)
#endif
#ifndef FLOG2
#define FLOG2(x) log2f(x)
#endif

typedef float f32x4 __attribute__((ext_vector_type(4)));
typedef short s16x4 __attribute__((ext_vector_type(4)));
typedef _Float16 h4 __attribute__((ext_vector_type(4)));

// bf16 pack, round-to-nearest-even, pure C (no asm)
__device__ __forceinline__ unsigned cvt2(float a, float b) {
#ifdef BF16MM
  const unsigned ua = __builtin_bit_cast(unsigned, a);
  const unsigned ub = __builtin_bit_cast(unsigned, b);
  const unsigned ra = (ua + 0x7FFFu + ((ua >> 16) & 1u)) >> 16;
  const unsigned rb = (ub + 0x7FFFu + ((ub >> 16) & 1u)) >> 16;
  return ra | (rb << 16);
#else
  return __builtin_bit_cast(unsigned,
      __builtin_amdgcn_cvt_pkrtz(fminf(a, 3.0e4f), fminf(b, 3.0e4f)));
#endif
}

__device__ __forceinline__ f32x4 MM(uint2 a, uint2 b, f32x4 c) {
#ifdef BF16MM
  return __builtin_amdgcn_mfma_f32_16x16x16bf16_1k(
      __builtin_bit_cast(s16x4, a), __builtin_bit_cast(s16x4, b), c, 0, 0, 0);
#else
  return __builtin_amdgcn_mfma_f32_16x16x16f16(
      __builtin_bit_cast(h4, a), __builtin_bit_cast(h4, b), c, 0, 0, 0);
#endif
}

// DPP lane shift: 0x138 = wave_shr:1, 0x130 = wave_shl:1 (boundary reads 0).
template<int CTRL>
__device__ __forceinline__ float dppf(float x) {
  return __builtin_bit_cast(float, __builtin_amdgcn_update_dpp(
      0, __builtin_bit_cast(int, x), CTRL, 0xf, 0xf, true));
}

// ---------------- numerator chain (R7 verbatim) ----------------------------
template<int DIR>
__device__ __forceinline__ void num_chain(const float* __restrict__ em,
                                          const float* __restrict__ TR,
                                          const int* __restrict__ Y,
                                          float* __restrict__ ws,
                                          const int b, const int l)
{
  const bool v0 = (2 * l     <= 100);
  const bool v1 = (2 * l + 1 <= 100);
  const int k0 = v0 ? 2 * l     : 100;
  const int k1 = v1 ? 2 * l + 1 : 100;
  const int y0 = Y[b * LL + k0];
  const int y1 = Y[b * LL + k1];
  const float SW0 = v0 ? FEXP2(TR[(y0 + 1) * NN + y0] * L2E) : 0.f;
  const float SW1 = v1 ? FEXP2(TR[(y1 + 1) * NN + y1] * L2E) : 0.f;
  float WLOC, WRECV, B0, B1, C;
  bool recvok;
  if (DIR == 0) {
    WLOC = v1 ? FEXP2(TR[(y1 + 1) * NN + y0] * L2E) : 0.f;
    const int ym0 = Y[b * LL + (k0 > 0 ? k0 - 1 : 0)];
    recvok = v0 && (l > 0);
    WRECV = recvok ? FEXP2(TR[(y0 + 1) * NN + ym0] * L2E) : 0.f;
    B0 = (l == 0) ? 1.f : 0.f;
    B1 = 0.f;
    C  = (l == 0) ? (TR[y0] + em[y0]) * L2E : 0.f;
  } else {
    WLOC = v1 ? FEXP2(TR[(y1 + 1) * NN + y0] * L2E) : 0.f;
    const int kp = (2 * l + 2 <= 100) ? 2 * l + 2 : 100;
    const int yp1 = Y[b * LL + kp];
    recvok = (2 * l + 2 <= 100);
    WRECV = recvok ? FEXP2(TR[(yp1 + 1) * NN + y1] * L2E) : 0.f;
    B0 = (l == 50) ? 1.f : 0.f;
    B1 = 0.f;
    C  = (l == 50) ? em[(size_t)(TT - 1) * NN + y0] * L2E : 0.f;
  }

#define TROW(t) ((size_t)((DIR == 0) ? (t) : (TT - 1 - (t))) * NN)

  float ca[8], cb[8], na[8], nb[8];
#pragma unroll
  for (int k = 0; k < 8; ++k) {
    ca[k] = em[TROW(1 + k) + y0];
    cb[k] = em[TROW(1 + k) + y1];
  }
#pragma unroll
  for (int k = 0; k < 8; ++k) {
    na[k] = em[TROW(9 + k) + y0];
    nb[k] = em[TROW(9 + k) + y1];
  }

  float ADJ = 0.f;

#define RESCALE()                                                              \
  {                                                                            \
    const float v = B0 + B1;                                                   \
    const int bits = __builtin_bit_cast(int, v);                               \
    const int m = (v > 0.f) ? ((bits >> 23) & 255) - 127 : 0;                  \
    const float sc = __builtin_bit_cast(float, (127 - m) << 23);               \
    B0 *= sc; B1 *= sc; C += (float)m;                                         \
    const float Cn = dppf<(DIR == 0) ? 0x138 : 0x130>(C);                      \
    const float dC = fminf(fmaxf(Cn - C, -120.f), 120.f);                      \
    ADJ = recvok ? FEXP2(dC) * WRECV : 0.f;                                    \
  }

#define NSTEP(EA, EB)                                                          \
  {                                                                            \
    const float E0 = FEXP2((EA) * L2E);                                        \
    const float E1 = FEXP2((EB) * L2E);                                        \
    if (DIR == 0) {                                                            \
      const float NB = dppf<0x138>(B1);                                        \
      const float t0 = fmaf(NB, ADJ, B0 * SW0);                                \
      const float t1 = fmaf(B0, WLOC, B1 * SW1);                               \
      B0 = t0 * E0; B1 = t1 * E1;                                              \
    } else {                                                                   \
      const float NB = dppf<0x130>(B0);                                        \
      const float t1 = fmaf(NB, ADJ, B1 * SW1);                                \
      const float t0 = fmaf(B1, WLOC, B0 * SW0);                               \
      B0 = t0 * E0; B1 = t1 * E1;                                              \
    }                                                                          \
  }

  for (int ep = 0; ep < 249; ++ep) {
    RESCALE();
    float pa[8], pb[8];
#pragma unroll
    for (int k = 0; k < 8; ++k) {
      int t = 17 + 8 * ep + k;
      t = (t < 1999) ? t : 1999;
      pa[k] = em[TROW(t) + y0];
      pb[k] = em[TROW(t) + y1];
    }
#pragma unroll
    for (int k = 0; k < 8; ++k) NSTEP(ca[k], cb[k]);
#pragma unroll
    for (int k = 0; k < 8; ++k) { ca[k] = na[k]; cb[k] = nb[k];
                                  na[k] = pa[k]; nb[k] = pb[k]; }
  }
  RESCALE();
#pragma unroll
  for (int k = 0; k < 7; ++k) NSTEP(ca[k], cb[k]);

#undef NSTEP
#undef RESCALE
#undef TROW

  const float o0 = (B0 > 1e-37f) ? C + FLOG2(B0) : NEG2;
  const float o1 = (B1 > 1e-37f) ? C + FLOG2(B1) : NEG2;
  const int base = (DIR ? WS_HB : WS_NF) + b * 112;
  if (v0) ws[base + 2 * l]     = o0;
  if (v1) ws[base + 2 * l + 1] = o1;
}

__global__ __launch_bounds__(128) void asg_main(
    const float* __restrict__ E, const float* __restrict__ TR,
    const int* __restrict__ Y, float* __restrict__ ws)
{
  const int bid  = blockIdx.x;
  const int w    = threadIdx.x >> 6;
  const int lane = threadIdx.x & 63;
  const int b    = bid >> 1;
  const float* em = E + (size_t)b * TT * NN;

  if (w == 0) {
    // ================= denominator: 16 segments via MFMA =================
    const int h = bid & 1;
    const int c = lane & 15, g = lane >> 4;
    const int j = h * 16 + c;                 // segment 0..31

    // A = W fragments: A[rt][kt] elem e = W[16rt+c][16kt+4g+e]
    uint2 Af[4][4];
#pragma unroll
    for (int rt = 0; rt < 4; ++rt)
#pragma unroll
      for (int kt = 0; kt < 4; ++kt) {
        const float* tr = TR + (size_t)(16 * rt + c + 1) * NN + 16 * kt + 4 * g;
        const float w0 = FEXP2(tr[0] * L2E), w1 = FEXP2(tr[1] * L2E);
        const float w2 = FEXP2(tr[2] * L2E), w3 = FEXP2(tr[3] * L2E);
        Af[rt][kt].x = cvt2(w0, w1);
        Af[rt][kt].y = cvt2(w2, w3);
      }

    // state P (C-layout): elem (rt,e) = P[16rt+4g+e][col c]
    f32x4 P[4];
#pragma unroll
    for (int rt = 0; rt < 4; ++rt)
#pragma unroll
      for (int e = 0; e < 4; ++e) {
        const int row = 16 * rt + 4 * g + e;
        P[rt][e] = (j == 0) ? FEXP2((em[row] + TR[row]) * L2E) : 1.0f;
      }

    float Csum = 0.f, snap31 = 0.f;
    const float* ebase = em + (size_t)(124 * j + 1) * NN + 4 * g;

#define COLSUM(dst) { float t_ =                                               \
      (P[0].x + P[0].y + P[0].z + P[0].w) + (P[1].x + P[1].y + P[1].z + P[1].w)\
    + (P[2].x + P[2].y + P[2].z + P[2].w) + (P[3].x + P[3].y + P[3].z + P[3].w);\
    t_ += __shfl_xor(t_, 16); t_ += __shfl_xor(t_, 32);                        \
    (dst) = fmaxf(t_, 1e-30f); }

#define RENORM() { float cs_; COLSUM(cs_);                                     \
    const int mb_ = ((__builtin_bit_cast(int, cs_) >> 23) & 255) - 127;        \
    const float sc_ = __builtin_bit_cast(float, (127 - mb_) << 23);            \
    P[0] *= sc_; P[1] *= sc_; P[2] *= sc_; P[3] *= sc_;                        \
    Csum += (float)mb_; }

#define ELOAD(D, s_) { const int se_ = (s_) < 154 ? (s_) : 154;                \
    const f32x4* p_ = (const f32x4*)(ebase + (size_t)se_ * NN);                \
    D[0] = p_[0]; D[1] = p_[4]; D[2] = p_[8]; D[3] = p_[12]; }

#define STEP(M)                                                                \
    {                                                                          \
      uint2 Bf[4];                                                             \
      _Pragma("unroll") for (int kt = 0; kt < 4; ++kt) {                       \
        Bf[kt].x = cvt2(P[kt].x, P[kt].y);                                     \
        Bf[kt].y = cvt2(P[kt].z, P[kt].w);                                     \
      }                                                                        \
      _Pragma("unroll") for (int rt = 0; rt < 4; ++rt) {                       \
        f32x4 acc = {0.f, 0.f, 0.f, 0.f};                                      \
        acc = MM(Af[rt][0], Bf[0], acc);                                       \
        acc = MM(Af[rt][1], Bf[1], acc);                                       \
        acc = MM(Af[rt][2], Bf[2], acc);                                       \
        acc = MM(Af[rt][3], Bf[3], acc);                                       \
        _Pragma("unroll") for (int e = 0; e < 4; ++e)                          \
          P[rt][e] = fminf(fmaxf(                                              \
              acc[e] * FEXP2(fmaf(M[rt][e], L2E, -6.7f)), 1e-20f), 1e25f);     \
      }                                                                        \
    }

#define SUB(Ebuf, ss)                                                          \
    { f32x4 T_[4] = {Ebuf[0], Ebuf[1], Ebuf[2], Ebuf[3]};                      \
      ELOAD(Ebuf, (ss) + 4);                                                   \
      STEP(T_);                                                                \
      if ((ss) == 30) { float cs2_; COLSUM(cs2_);                              \
                        snap31 = Csum + FLOG2(cs2_) + 6.7f * 31.f; }           \
      if (((ss) & 7) == 7) RENORM(); }

    f32x4 E0[4], E1[4], E2[4], E3[4];
    ELOAD(E0, 0); ELOAD(E1, 1); ELOAD(E2, 2); ELOAD(E3, 3);

    for (int it = 0; it < 38; ++it) {        // steps s = 0..151
      const int s = 4 * it;
      SUB(E0, s); SUB(E1, s + 1); SUB(E2, s + 2); SUB(E3, s + 3);
    }
    { f32x4 T_[4] = {E0[0], E0[1], E0[2], E0[3]}; STEP(T_); }   // s=152
    { f32x4 T_[4] = {E1[0], E1[1], E1[2], E1[3]}; STEP(T_); }   // s=153
    { f32x4 T_[4] = {E2[0], E2[1], E2[2], E2[3]}; STEP(T_); }   // s=154

    float csf; COLSUM(csf);
    const float fin = Csum + FLOG2(csf) + 6.7f * 155.f;
    const float X = fin - ((j == 0) ? 0.f : snap31);
    if (lane < 16) ws[WS_X + b * NSEG + (h * 16 + lane)] = X;

#undef SUB
#undef STEP
#undef ELOAD
#undef RENORM
#undef COLSUM

  } else {
    // ================= numerator (R7 verbatim) ============================
    const int dir = bid & 1;
    if (dir == 0) num_chain<0>(em, TR, Y, ws, b, lane);
    else          num_chain<1>(em, TR, Y, ws, b, lane);
  }
}

__global__ __launch_bounds__(128) void asg_combine(
    const float* __restrict__ TR, const int* __restrict__ Y,
    const float* __restrict__ ws, float* __restrict__ lossv)
{
  const int b = blockIdx.x;
  const int tid = threadIdx.x;
  __shared__ float sN[LL], sH[LL], red[128];
  __shared__ float sLogZ;

  if (tid == 0) {
    float z = 0.f;
    for (int s = 0; s < NSEG; ++s) z += ws[WS_X + b * NSEG + s];
    sLogZ = z;                              // log2 Z
  }
  if (tid < LL) { sN[tid] = ws[WS_NF + b * 112 + tid]; sH[tid] = ws[WS_HB + b * 112 + tid]; }
  __syncthreads();

  float val2 = -3.0e38f;
  if (tid < LL) {
    const int l = tid;
    const int y = Y[b * LL + l];
    const float s1 = sN[l] + TR[(y + 1) * NN + y] * L2E;
    float s2 = NEG2;
    if (l > 0) {
      const int ymm = Y[b * LL + l - 1];
      s2 = sN[l - 1] + TR[(y + 1) * NN + ymm] * L2E;
    }
    const float m = fmaxf(s1, s2);
    val2 = m + log2f(exp2f(s1 - m) + exp2f(s2 - m)) + sH[l];
  }
  red[tid] = val2;
  __syncthreads();
  if (tid == 0) {
    float m = red[0];
    for (int k = 1; k < LL; ++k) m = fmaxf(m, red[k]);
    float s = 0.f;
    for (int k = 0; k < LL; ++k) s += exp2f(red[k] - m);
    const float tgt2 = m + log2f(s);
    lossv[b] = (sLogZ - tgt2) * LN2F / (float)LL;
  }
}

__global__ __launch_bounds__(64) void asg_reduce(const float* __restrict__ lossv,
                                                 float* __restrict__ out)
{
  const int tid = threadIdx.x;
  float v = lossv[tid] + lossv[tid + 64];
  for (int off = 32; off; off >>= 1) v += __shfl_xor(v, off);
  if (tid == 0) out[0] = v * (1.0f / 128.0f);
}

extern "C" void kernel_launch(void* const* d_in, const int* in_sizes, int n_in,
                              void* d_out, int out_size, void* d_ws, size_t ws_size,
                              hipStream_t stream) {
  const float* E  = (const float*)d_in[0];
  const float* TR = (const float*)d_in[1];
  const int*   Y  = (const int*)d_in[2];
  float* out = (float*)d_out;
  float* ws  = (float*)d_ws;
  float* lossv = ws + WS_LOSS;

  // 256 blocks x 2 waves: wave0 = den (16 MFMA segments), wave1 = num chain.
  asg_main<<<dim3(256), dim3(128), 0, stream>>>(E, TR, Y, ws);
  asg_combine<<<dim3(128), dim3(128), 0, stream>>>(TR, Y, ws, lossv);
  asg_reduce<<<dim3(1), dim3(64), 0, stream>>>(lossv, out);
}